// Round 2
// baseline (19.708 us; speedup 1.0000x reference)
//
#include <hip/hip_runtime.h>
#include <math.h>

// B=64, L=100, D=16, N=1024. Output y[b,l,d] f32 (102400 elems).
//
// Algebraic collapse: dA is multiplied by 0 (h init), so
//   y[t,d] = x[t,d] * softplus(x[t]·W1[:,d] + b1[d]) * s(t)
//   s(t)   = v^T M v + uv·v + c,   v = x[t,:]
//   M = W2 W3^T (16x16), uv[i] = Σ_n W2[i,n]b3[n]+W3[i,n]b2[n], c = b2·b3.
//
// Single-kernel version: every block recomputes M via bf16 MFMA (split-K
// over its 4 waves, fragments loaded straight from global: each lane's
// 8 K-elements are 32B contiguous of a W2/W3 row), reduces partials in
// LDS, then processes 64 tokens. Avoids the 2-dependent-launch latency.

#define DD 16
#define NN 1024
#define TOKS 64          // tokens per block
#define NBLK 100         // 6400 / 64

typedef __attribute__((ext_vector_type(8))) short bf16x8;
typedef __attribute__((ext_vector_type(4))) float f32x4;

static __device__ inline short f2bf(float f) {     // f32 -> bf16 RNE
    union { float f; unsigned u; } v; v.f = f;
    unsigned r = v.u + 0x7FFFu + ((v.u >> 16) & 1u);
    return (short)(r >> 16);
}

__global__ __launch_bounds__(256) void s6_all(
    const float* __restrict__ x,  const float* __restrict__ W1,
    const float* __restrict__ b1,
    const float* __restrict__ W2, const float* __restrict__ b2,
    const float* __restrict__ W3, const float* __restrict__ b3,
    float* __restrict__ out)
{
    __shared__ float xs[TOKS * DD];      // 4 KB  (64 tokens x 16)
    __shared__ float w1s[256];           // W1[k*16+d]
    __shared__ float b1s[DD];
    __shared__ float part[4][256];       // per-wave M partials
    __shared__ float ms[DD * 17];        // M padded (17) for bank spread
    __shared__ float uvs[DD];
    __shared__ float cs;

    const int tid  = threadIdx.x;
    const int wv   = tid >> 6;
    const int lane = tid & 63;
    const int base = blockIdx.x * (TOKS * DD);

    // ---- stage x tile (coalesced float4) + W1 + b1 ----
    *(float4*)(xs + tid * 4) = *(const float4*)(x + base + tid * 4);
    w1s[tid] = W1[tid];
    if (tid < DD) b1s[tid] = b1[tid];

    // ---- M = W2 W3^T via bf16 MFMA, split-K: wave wv owns K-slice wv*256 ----
    {
        const int r  = lane & 15;        // A row (W2 row) == B col (W3 row)
        const int kg = lane >> 4;        // k-group 0..3
        const float* a_base = W2 + r * NN + wv * 256 + kg * 8;
        const float* b_base = W3 + r * NN + wv * 256 + kg * 8;
        f32x4 acc = {0.f, 0.f, 0.f, 0.f};
        #pragma unroll
        for (int kk = 0; kk < 8; ++kk) {
            float4 a0 = *(const float4*)(a_base + kk * 32);
            float4 a1 = *(const float4*)(a_base + kk * 32 + 4);
            float4 c0 = *(const float4*)(b_base + kk * 32);
            float4 c1 = *(const float4*)(b_base + kk * 32 + 4);
            bf16x8 af, bf;
            af[0]=f2bf(a0.x); af[1]=f2bf(a0.y); af[2]=f2bf(a0.z); af[3]=f2bf(a0.w);
            af[4]=f2bf(a1.x); af[5]=f2bf(a1.y); af[6]=f2bf(a1.z); af[7]=f2bf(a1.w);
            bf[0]=f2bf(c0.x); bf[1]=f2bf(c0.y); bf[2]=f2bf(c0.z); bf[3]=f2bf(c0.w);
            bf[4]=f2bf(c1.x); bf[5]=f2bf(c1.y); bf[6]=f2bf(c1.z); bf[7]=f2bf(c1.w);
            acc = __builtin_amdgcn_mfma_f32_16x16x32_bf16(af, bf, acc, 0, 0, 0);
        }
        // C/D layout (m89-verified): col = lane&15, row = (lane>>4)*4 + ri
        #pragma unroll
        for (int ri = 0; ri < 4; ++ri)
            part[wv][((lane >> 4) * 4 + ri) * 16 + (lane & 15)] = acc[ri];
    }

    // ---- uv[i] and c partials in f32 (b2/b3 paths kept exact) ----
    {
        const int i = tid >> 4, d = tid & 15;
        const float* r2 = W2 + i * NN + d * 64;
        const float* r3 = W3 + i * NN + d * 64;
        const float* p2 = b2 + d * 64;
        const float* p3 = b3 + d * 64;
        float uvp = 0.f, cp = 0.f;
        #pragma unroll
        for (int t = 0; t < 16; ++t) {
            float4 a2 = *(const float4*)(r2 + t * 4);
            float4 a3 = *(const float4*)(r3 + t * 4);
            float4 v2 = *(const float4*)(p2 + t * 4);
            float4 v3 = *(const float4*)(p3 + t * 4);
            uvp += a2.x*v3.x + a2.y*v3.y + a2.z*v3.z + a2.w*v3.w
                 + a3.x*v2.x + a3.y*v2.y + a3.z*v2.z + a3.w*v2.w;
            cp  += v2.x*v3.x + v2.y*v3.y + v2.z*v3.z + v2.w*v3.w;
        }
        #pragma unroll
        for (int o = 1; o < 16; o <<= 1) {
            uvp += __shfl_xor(uvp, o, 64);
            cp  += __shfl_xor(cp,  o, 64);
        }
        if (d == 0) uvs[i] = uvp;
        if (tid == 0) cs = cp;
    }

    __syncthreads();

    // ---- reduce the 4 split-K partials into padded M ----
    ms[(tid >> 4) * 17 + (tid & 15)] =
        part[0][tid] + part[1][tid] + part[2][tid] + part[3][tid];

    __syncthreads();

    // ---- token phase: 16 tokens x 16 lanes per pass, 4 passes ----
    const int g = tid >> 4, d = tid & 15;
    const float c = cs;
    #pragma unroll
    for (int tt = 0; tt < TOKS / 16; ++tt) {
        const float* vv = xs + (tt * 16 + g) * DD;
        float v[DD];
        #pragma unroll
        for (int k = 0; k < DD; ++k) v[k] = vv[k];

        // delta_d = softplus(b1[d] + v · W1[:,d])
        float td = b1s[d];
        #pragma unroll
        for (int k = 0; k < DD; ++k) td = fmaf(v[k], w1s[k * DD + d], td);
        const float delta = fmaxf(td, 0.f) + log1pf(expf(-fabsf(td)));

        // s = Σ_d v[d]*(M[d,:]·v + uv[d]) + c   (16-lane reduce)
        float row = uvs[d];
        #pragma unroll
        for (int j = 0; j < DD; ++j) row = fmaf(ms[d * 17 + j], v[j], row);
        float p = v[d] * row;
        #pragma unroll
        for (int o = 1; o < 16; o <<= 1) p += __shfl_xor(p, o, 64);

        out[base + tt * 256 + tid] = v[d] * delta * (p + c);
    }
}

extern "C" void kernel_launch(void* const* d_in, const int* in_sizes, int n_in,
                              void* d_out, int out_size, void* d_ws, size_t ws_size,
                              hipStream_t stream) {
    const float* x  = (const float*)d_in[0];
    const float* W1 = (const float*)d_in[1];
    const float* b1 = (const float*)d_in[2];
    const float* W2 = (const float*)d_in[3];
    const float* b2 = (const float*)d_in[4];
    const float* W3 = (const float*)d_in[5];
    const float* b3 = (const float*)d_in[6];
    // d_in[7] = A_log: dead in the reference (dA * 0.0), intentionally unused.
    float* out = (float*)d_out;

    s6_all<<<NBLK, 256, 0, stream>>>(x, W1, b1, W2, b2, W3, b3, out);
}

// Round 3
// 12.360 us; speedup vs baseline: 1.5946x; 1.5946x over previous
//
#include <hip/hip_runtime.h>
#include <hip/hip_bf16.h>
#include <math.h>

// B=64, L=100, D=16, N=1024. Output y[b,l,d] f32 (102400 elems).
//
// Algebraic collapse: dA is multiplied by 0 (h init in the reference), so
//   y[t,d] = x[t,d] * softplus(x[t]·W1[:,d] + b1[d]) * s(t)
//   s(t)   = v^T M v + uv·v + c,   v = x[t,:]
//   M = W2 W3^T (16x16), uv[j] = Σ_n b3[n]W2[j,n] + b2[n]W3[j,n], c = b2·b3.
//
// One lean kernel, 200 blocks x 256 threads (32 tokens/block). Each block
// recomputes M via bf16 MFMA (split-K over 4 waves, fragments loaded straight
// from global: a lane's 8 K-elems are 32B contiguous of a W2/W3 row). uv is
// folded into the SAME pass by a sparse A-fragment S (row0=b3, row1=b2,
// rest 0) against the already-loaded W2/W3 fragments -> no second weight read.

#define DD 16
#define NN 1024
#define TOKS 32
#define NBLK 200         // 6400 / 32

typedef __attribute__((ext_vector_type(8))) short bf16x8;
typedef __attribute__((ext_vector_type(4))) float f32x4;

static __device__ inline short bfs(float f) {        // RNE via HW cvt
    __hip_bfloat16 h = __float2bfloat16(f);
    return *reinterpret_cast<short*>(&h);
}

__global__ __launch_bounds__(256) void s6_one(
    const float* __restrict__ x,  const float* __restrict__ W1,
    const float* __restrict__ b1,
    const float* __restrict__ W2, const float* __restrict__ b2,
    const float* __restrict__ W3, const float* __restrict__ b3,
    float* __restrict__ out)
{
    __shared__ float xs[TOKS * DD];      // 2 KB
    __shared__ float w1s[256];
    __shared__ float b1s[DD];
    __shared__ float part[4][256];       // per-wave M partials
    __shared__ float uvp[4][DD];
    __shared__ float cp4[4];
    __shared__ float ms[DD * 17];        // padded M

    const int tid  = threadIdx.x;
    const int wv   = tid >> 6;
    const int lane = tid & 63;
    const int base = blockIdx.x * (TOKS * DD);

    // ---- stage x tile / W1 / b1 (cheap, off the critical path) ----
    if (tid < 128) *(float4*)(xs + tid * 4) = *(const float4*)(x + base + tid * 4);
    w1s[tid] = W1[tid];
    if (tid < DD) b1s[tid] = b1[tid];

    // ---- split-K MFMA phase: wave wv owns K-slice [wv*256, wv*256+256) ----
    {
        const int r  = lane & 15;        // fragment row
        const int kg = lane >> 4;        // k-group 0..3 (8 elems each)
        const float* a_base = W2 + r * NN + wv * 256 + kg * 8;
        const float* b_base = W3 + r * NN + wv * 256 + kg * 8;
        const float* s_base = (r == 0) ? (b3 + wv * 256 + kg * 8)
                            : (r == 1) ? (b2 + wv * 256 + kg * 8) : nullptr;

        f32x4 accM  = {0.f, 0.f, 0.f, 0.f};
        f32x4 accU1 = {0.f, 0.f, 0.f, 0.f};   // S · W2^T  (row0 = b3·W2[j])
        f32x4 accU2 = {0.f, 0.f, 0.f, 0.f};   // S · W3^T  (row1 = b2·W3[j])
        float cpart = 0.f;
        {   // c = b2·b3 partial: this lane's 4 elems of the wave's K-slice
            float4 v2 = *(const float4*)(b2 + wv * 256 + lane * 4);
            float4 v3 = *(const float4*)(b3 + wv * 256 + lane * 4);
            cpart = v2.x*v3.x + v2.y*v3.y + v2.z*v3.z + v2.w*v3.w;
        }

        #pragma unroll
        for (int kk = 0; kk < 8; ++kk) {
            float4 a0 = *(const float4*)(a_base + kk * 32);
            float4 a1 = *(const float4*)(a_base + kk * 32 + 4);
            float4 c0 = *(const float4*)(b_base + kk * 32);
            float4 c1 = *(const float4*)(b_base + kk * 32 + 4);
            bf16x8 af, bf;
            af[0]=bfs(a0.x); af[1]=bfs(a0.y); af[2]=bfs(a0.z); af[3]=bfs(a0.w);
            af[4]=bfs(a1.x); af[5]=bfs(a1.y); af[6]=bfs(a1.z); af[7]=bfs(a1.w);
            bf[0]=bfs(c0.x); bf[1]=bfs(c0.y); bf[2]=bfs(c0.z); bf[3]=bfs(c0.w);
            bf[4]=bfs(c1.x); bf[5]=bfs(c1.y); bf[6]=bfs(c1.z); bf[7]=bfs(c1.w);

            bf16x8 sf = {0,0,0,0,0,0,0,0};
            if (s_base) {
                float4 s0 = *(const float4*)(s_base + kk * 32);
                float4 s1 = *(const float4*)(s_base + kk * 32 + 4);
                sf[0]=bfs(s0.x); sf[1]=bfs(s0.y); sf[2]=bfs(s0.z); sf[3]=bfs(s0.w);
                sf[4]=bfs(s1.x); sf[5]=bfs(s1.y); sf[6]=bfs(s1.z); sf[7]=bfs(s1.w);
            }
            accM  = __builtin_amdgcn_mfma_f32_16x16x32_bf16(af, bf, accM,  0, 0, 0);
            accU1 = __builtin_amdgcn_mfma_f32_16x16x32_bf16(sf, af, accU1, 0, 0, 0);
            accU2 = __builtin_amdgcn_mfma_f32_16x16x32_bf16(sf, bf, accU2, 0, 0, 0);
        }

        // C/D layout: col = lane&15, row = (lane>>4)*4 + ri
        #pragma unroll
        for (int ri = 0; ri < 4; ++ri)
            part[wv][((lane >> 4) * 4 + ri) * 16 + (lane & 15)] = accM[ri];
        if (lane < 16) uvp[wv][lane] = accU1[0] + accU2[1];  // rows 0 and 1

        #pragma unroll
        for (int o = 32; o >= 1; o >>= 1) cpart += __shfl_xor(cpart, o, 64);
        if (lane == 0) cp4[wv] = cpart;
    }

    __syncthreads();

    // ---- fold split-K partials into padded M ----
    ms[(tid >> 4) * 17 + (tid & 15)] =
        part[0][tid] + part[1][tid] + part[2][tid] + part[3][tid];

    __syncthreads();

    // ---- token phase: 16 tokens x 16 lanes per pass ----
    const int g = tid >> 4, d = tid & 15;
    const float c   = cp4[0] + cp4[1] + cp4[2] + cp4[3];
    const float uvd = uvp[0][d] + uvp[1][d] + uvp[2][d] + uvp[3][d];

    #pragma unroll
    for (int tt = 0; tt < TOKS / 16; ++tt) {
        const float* vv = xs + (tt * 16 + g) * DD;
        float v[DD];
        #pragma unroll
        for (int k = 0; k < DD; ++k) v[k] = vv[k];

        // delta_d = softplus(b1[d] + v · W1[:,d])
        float td = b1s[d];
        #pragma unroll
        for (int k = 0; k < DD; ++k) td = fmaf(v[k], w1s[k * DD + d], td);
        const float delta = fmaxf(td, 0.f) + log1pf(expf(-fabsf(td)));

        // s = Σ_d v[d]*(M[d,:]·v + uv[d]) + c   (16-lane reduce)
        float row = uvd;
        #pragma unroll
        for (int j = 0; j < DD; ++j) row = fmaf(ms[d * 17 + j], v[j], row);
        float p = v[d] * row;
        #pragma unroll
        for (int o = 1; o < 16; o <<= 1) p += __shfl_xor(p, o, 64);

        out[base + tt * 256 + tid] = v[d] * delta * (p + c);
    }
}

extern "C" void kernel_launch(void* const* d_in, const int* in_sizes, int n_in,
                              void* d_out, int out_size, void* d_ws, size_t ws_size,
                              hipStream_t stream) {
    const float* x  = (const float*)d_in[0];
    const float* W1 = (const float*)d_in[1];
    const float* b1 = (const float*)d_in[2];
    const float* W2 = (const float*)d_in[3];
    const float* b2 = (const float*)d_in[4];
    const float* W3 = (const float*)d_in[5];
    const float* b3 = (const float*)d_in[6];
    // d_in[7] = A_log: dead in the reference (dA * 0.0), intentionally unused.
    float* out = (float*)d_out;

    s6_one<<<NBLK, 256, 0, stream>>>(x, W1, b1, W2, b2, W3, b3, out);
}